// Round 6
// baseline (242.113 us; speedup 1.0000x reference)
//
#include <hip/hip_runtime.h>
#include <hip/hip_fp16.h>
#include <math.h>

#define EMB_DIM 128
#define FINE_BITS 6
#define FINE_W 64           // nodes per dest bucket (= one K3 block)
#define MAXB 2048           // max coarse buckets (N <= 131072)
#define CHUNK 16384         // edges per scatter block (long runs per bucket ->
                            // less write-allocate waste, 4x fewer cursor atomics)
#define MAX_SLACK 4096      // LDS sortedR capacity (slack clamped to this)

// ---------------------------------------------------------------------------
// K1 (fused): blocks [0,nchunks): col-side coarse scatter; [nchunks,2*nchunks):
// row-side coarse scatter; [2*nchunks, ...): f32->fp16 embedding convert.
// Cursors are RELATIVE (zeroed by memset); absolute base = bucket*slack.
// All LDS atomics here are INTEGER (native ds_add) — never FP.
__global__ __launch_bounds__(256) void scatter_cvt_kernel(
    const int* __restrict__ row, const int* __restrict__ col,
    int* __restrict__ colCur, int* __restrict__ rowCur,
    unsigned int* __restrict__ colBucket, unsigned char* __restrict__ rowBucket,
    const float* __restrict__ emb, __half* __restrict__ emb16, long long n8,
    int slack, int nchunks, int e) {
    int bid = blockIdx.x;
    if (bid >= 2 * nchunks) {
        // ---- cvt tail: 8 floats -> 8 halves per thread ----
        long long t = (long long)(bid - 2 * nchunks) * 256 + threadIdx.x;
        if (t < n8) {
            const float4* src = (const float4*)(emb) + t * 2;
            float4 a = src[0];
            float4 b = src[1];
            __half h[8];
            h[0] = __float2half(a.x); h[1] = __float2half(a.y);
            h[2] = __float2half(a.z); h[3] = __float2half(a.w);
            h[4] = __float2half(b.x); h[5] = __float2half(b.y);
            h[6] = __float2half(b.z); h[7] = __float2half(b.w);
            ((uint4*)emb16)[t] = *(const uint4*)h;
        }
        return;
    }
    __shared__ int lh[MAXB], lb[MAXB];
    bool doRow = bid >= nchunks;
    int chunk = doRow ? bid - nchunks : bid;
    int base = chunk * CHUNK;
    int lim = min(base + CHUNK, e);

    for (int t = threadIdx.x; t < MAXB; t += 256) lh[t] = 0;
    __syncthreads();
    if (!doRow) {
        for (int i = base + threadIdx.x; i < lim; i += 256)
            atomicAdd(&lh[col[i] >> FINE_BITS], 1);
        __syncthreads();
        for (int t = threadIdx.x; t < MAXB; t += 256)
            lb[t] = lh[t] ? (t * slack + atomicAdd(&colCur[t], lh[t])) : 0;
        __syncthreads();
        for (int t = threadIdx.x; t < MAXB; t += 256) lh[t] = 0;
        __syncthreads();
        for (int i = base + threadIdx.x; i < lim; i += 256) {
            int c = col[i], r = row[i];
            int cb = c >> FINE_BITS;
            int p = lb[cb] + atomicAdd(&lh[cb], 1);
            if (p < (cb + 1) * slack)
                colBucket[p] = ((unsigned)r << FINE_BITS) | (unsigned)(c & (FINE_W - 1));
        }
    } else {
        for (int i = base + threadIdx.x; i < lim; i += 256)
            atomicAdd(&lh[row[i] >> FINE_BITS], 1);
        __syncthreads();
        for (int t = threadIdx.x; t < MAXB; t += 256)
            lb[t] = lh[t] ? (t * slack + atomicAdd(&rowCur[t], lh[t])) : 0;
        __syncthreads();
        for (int t = threadIdx.x; t < MAXB; t += 256) lh[t] = 0;
        __syncthreads();
        for (int i = base + threadIdx.x; i < lim; i += 256) {
            int r = row[i];
            int rb = r >> FINE_BITS;
            int q = lb[rb] + atomicAdd(&lh[rb], 1);
            if (q < (rb + 1) * slack)
                rowBucket[q] = (unsigned char)(r & (FINE_W - 1));
        }
    }
}

// ---------------------------------------------------------------------------
// K2: row-side fine histogram -> dis = rsqrt(1+deg). One block per bucket.
__global__ __launch_bounds__(256) void deg_kernel(
    const unsigned char* __restrict__ rowBucket, const int* __restrict__ rowCurF,
    float* __restrict__ dis, int slack, int n) {
    __shared__ int fh[FINE_W];
    int b = blockIdx.x;
    unsigned t = threadIdx.x;
    int start = b * slack;
    int end = start + min(rowCurF[b], slack);
    if (t < FINE_W) fh[t] = 0;
    __syncthreads();
    for (int i = start + (int)t; i < end; i += 256)
        atomicAdd(&fh[rowBucket[i]], 1);
    __syncthreads();
    if (t < FINE_W) {
        int node = (b << FINE_BITS) + (int)t;
        if (node < n) dis[node] = rsqrtf(1.0f + (float)fh[t]);
    }
}

// ---------------------------------------------------------------------------
// K3: bucket gather, register accumulation (NO fp atomics — round-4 lesson:
// float atomicAdd on LDS lowers to a CAS loop, 17x slowdown).
// One 512-thread block per 64-node bucket:
//   phase 1: in-block counting sort of the bucket's ~1K edges by fine node;
//   phase 2: 64 groups x 8 lanes; group g accumulates node g's contiguous
//            edge range in registers, unroll-4 (8 x 16B loads in flight/lane).
// Self-loop folded into accumulator init (norm = dis^2).
template <bool FP16>
__global__ __launch_bounds__(512) void gather_kernel(
    const __half* __restrict__ emb16, const float* __restrict__ emb,
    const float* __restrict__ dis, const unsigned int* __restrict__ colBucket,
    const int* __restrict__ colCurF, float* __restrict__ out,
    int slack, int n) {
    __shared__ int binCnt[FINE_W];
    __shared__ int binStart[FINE_W];
    __shared__ int binCur[FINE_W];
    __shared__ int sortedR[MAX_SLACK];
    __shared__ float disl[FINE_W];
    int b = blockIdx.x;
    int tid = threadIdx.x;
    int nodeBase = b << FINE_BITS;
    int start = b * slack;
    int cnt = min(colCurF[b], slack);

    if (tid < FINE_W) {
        binCnt[tid] = 0;
        int node = nodeBase + tid;
        disl[tid] = (node < n) ? dis[node] : 0.0f;
    }
    __syncthreads();

    // ---- phase 1a: fine histogram (coalesced global read, int LDS atomics)
    for (int i = tid; i < cnt; i += 512)
        atomicAdd(&binCnt[colBucket[start + i] & (FINE_W - 1)], 1);
    __syncthreads();

    // ---- phase 1b: exclusive scan of 64 bins entirely inside wave 0
    if (tid < FINE_W) {
        int v = binCnt[tid];
        int incl = v;
        #pragma unroll
        for (int d = 1; d < FINE_W; d <<= 1) {
            int u = __shfl_up(incl, d, FINE_W);
            if (tid >= d) incl += u;
        }
        binStart[tid] = incl - v;
        binCur[tid] = incl - v;
    }
    __syncthreads();

    // ---- phase 1c: scatter source ids into node-contiguous LDS order
    //      (re-read colBucket: the chunk is L1/L2 hot)
    for (int i = tid; i < cnt; i += 512) {
        unsigned v = colBucket[start + i];
        int p = atomicAdd(&binCur[v & (FINE_W - 1)], 1);
        sortedR[p] = (int)(v >> FINE_BITS);
    }
    __syncthreads();

    // ---- phase 2: register accumulation, 8 lanes per node, 16 dims/lane
    int g = tid >> 3;        // node within bucket
    int lane = tid & 7;
    int node = nodeBase + g;
    int node_s = (node < n) ? node : 0;
    float dc = disl[g];
    float s = dc * dc;
    float4 acc0, acc1, acc2, acc3;

#define ACCUM_FP16(SRC, NRM)                                                    \
    {                                                                           \
        const uint4* hrow = (const uint4*)(emb16 + (long long)(SRC) * EMB_DIM); \
        uint4 ha = hrow[lane];                                                  \
        uint4 hb = hrow[lane + 8];                                              \
        const __half2* pa = (const __half2*)&ha;                                \
        const __half2* pb = (const __half2*)&hb;                                \
        float2 f0 = __half22float2(pa[0]), f1 = __half22float2(pa[1]);          \
        float2 f2 = __half22float2(pa[2]), f3 = __half22float2(pa[3]);          \
        float2 g0 = __half22float2(pb[0]), g1 = __half22float2(pb[1]);          \
        float2 g2 = __half22float2(pb[2]), g3 = __half22float2(pb[3]);          \
        acc0.x += (NRM) * f0.x; acc0.y += (NRM) * f0.y;                         \
        acc0.z += (NRM) * f1.x; acc0.w += (NRM) * f1.y;                         \
        acc1.x += (NRM) * f2.x; acc1.y += (NRM) * f2.y;                         \
        acc1.z += (NRM) * f3.x; acc1.w += (NRM) * f3.y;                         \
        acc2.x += (NRM) * g0.x; acc2.y += (NRM) * g0.y;                         \
        acc2.z += (NRM) * g1.x; acc2.w += (NRM) * g1.y;                         \
        acc3.x += (NRM) * g2.x; acc3.y += (NRM) * g2.y;                         \
        acc3.z += (NRM) * g3.x; acc3.w += (NRM) * g3.y;                         \
    }

#define ACCUM_FP32(SRC, NRM)                                                    \
    {                                                                           \
        const float4* frow = (const float4*)(emb + (long long)(SRC) * EMB_DIM); \
        float4 v0 = frow[2 * lane];                                             \
        float4 v1 = frow[2 * lane + 1];                                         \
        float4 v2 = frow[16 + 2 * lane];                                        \
        float4 v3 = frow[16 + 2 * lane + 1];                                    \
        acc0.x += (NRM) * v0.x; acc0.y += (NRM) * v0.y;                         \
        acc0.z += (NRM) * v0.z; acc0.w += (NRM) * v0.w;                         \
        acc1.x += (NRM) * v1.x; acc1.y += (NRM) * v1.y;                         \
        acc1.z += (NRM) * v1.z; acc1.w += (NRM) * v1.w;                         \
        acc2.x += (NRM) * v2.x; acc2.y += (NRM) * v2.y;                         \
        acc2.z += (NRM) * v2.z; acc2.w += (NRM) * v2.w;                         \
        acc3.x += (NRM) * v3.x; acc3.y += (NRM) * v3.y;                         \
        acc3.z += (NRM) * v3.z; acc3.w += (NRM) * v3.w;                         \
    }

    // self-loop init: acc = dis^2 * emb[node] (s==0 for padding rows)
    acc0 = acc1 = acc2 = acc3 = float4{0, 0, 0, 0};
    if (FP16) { ACCUM_FP16(node_s, s); } else { ACCUM_FP32(node_s, s); }

    int i = binStart[g];
    int end = i + binCnt[g];
    for (; i + 4 <= end; i += 4) {
        int s0 = sortedR[i], s1 = sortedR[i + 1];
        int s2 = sortedR[i + 2], s3 = sortedR[i + 3];
        float n0 = dc * dis[s0];
        float n1 = dc * dis[s1];
        float n2 = dc * dis[s2];
        float n3 = dc * dis[s3];
        if (FP16) { ACCUM_FP16(s0, n0); ACCUM_FP16(s1, n1);
                    ACCUM_FP16(s2, n2); ACCUM_FP16(s3, n3); }
        else      { ACCUM_FP32(s0, n0); ACCUM_FP32(s1, n1);
                    ACCUM_FP32(s2, n2); ACCUM_FP32(s3, n3); }
    }
    for (; i + 2 <= end; i += 2) {
        int s0 = sortedR[i], s1 = sortedR[i + 1];
        float n0 = dc * dis[s0];
        float n1 = dc * dis[s1];
        if (FP16) { ACCUM_FP16(s0, n0); ACCUM_FP16(s1, n1); }
        else      { ACCUM_FP32(s0, n0); ACCUM_FP32(s1, n1); }
    }
    if (i < end) {
        int s0 = sortedR[i];
        float n0 = dc * dis[s0];
        if (FP16) { ACCUM_FP16(s0, n0); } else { ACCUM_FP32(s0, n0); }
    }
#undef ACCUM_FP16
#undef ACCUM_FP32

    if (node < n) {
        float4* orow = (float4*)(out + (long long)node * EMB_DIM);
        orow[2 * lane] = acc0;
        orow[2 * lane + 1] = acc1;
        orow[16 + 2 * lane] = acc2;
        orow[16 + 2 * lane + 1] = acc3;
    }
}

extern "C" void kernel_launch(void* const* d_in, const int* in_sizes, int n_in,
                              void* d_out, int out_size, void* d_ws, size_t ws_size,
                              hipStream_t stream) {
    const int E = in_sizes[0] / 2;            // edge_index is (2, E) int32
    const int N = in_sizes[1] / EMB_DIM;      // embedding is (N, 128) f32
    const int nbuck = (N + FINE_W - 1) >> FINE_BITS;   // 1563 for N=100000

    const int* edge_index = (const int*)d_in[0];
    const int* row = edge_index;              // sources
    const int* col = edge_index + E;          // destinations
    const float* emb = (const float*)d_in[1];
    float* out = (float*)d_out;

    // slack per bucket: mean + 25% + 1024 (>>10 sigma for random edges),
    // clamped to the K3 LDS sort capacity.
    const int expected = (int)(((long long)E * FINE_W + N - 1) / N);
    int slack = expected + (expected >> 2) + 1024;
    if (slack > MAX_SLACK) slack = MAX_SLACK;
    const size_t bucketEntries = (size_t)nbuck * slack;

    char* ws = (char*)d_ws;
    size_t off = 0;
    auto alloc = [&](size_t bytes) -> void* {
        off = (off + 255) & ~(size_t)255;
        void* p = ws + off;
        off += bytes;
        return p;
    };

    size_t szEmb16 = (size_t)N * EMB_DIM * 2;
    size_t needCommon = (size_t)MAXB * 8 + (size_t)N * 4 +
                        bucketEntries * 5 + 16 * 256;
    bool useFp16 = (needCommon + szEmb16) <= ws_size;

    int*            colCur    = (int*)alloc((size_t)MAXB * 4);
    int*            rowCur    = (int*)alloc((size_t)MAXB * 4);   // adjacent to colCur
    float*          dis       = (float*)alloc((size_t)N * 4);
    unsigned int*   colBucket = (unsigned int*)alloc(bucketEntries * 4);
    unsigned char*  rowBucket = (unsigned char*)alloc(bucketEntries);
    __half*         emb16     = useFp16 ? (__half*)alloc(szEmb16) : (__half*)nullptr;

    const int B = 256;
    const int nchunks = (E + CHUNK - 1) / CHUNK;
    long long n8 = useFp16 ? (long long)N * EMB_DIM / 8 : 0;
    int cvtBlocks = useFp16 ? (int)((n8 + B - 1) / B) : 0;

    // zero both relative cursor arrays (adjacent, MAXB*4 each, 256-aligned)
    hipMemsetAsync(colCur, 0, (size_t)MAXB * 8, stream);

    scatter_cvt_kernel<<<2 * nchunks + cvtBlocks, B, 0, stream>>>(
        row, col, colCur, rowCur, colBucket, rowBucket,
        emb, emb16, n8, slack, nchunks, E);

    deg_kernel<<<nbuck, B, 0, stream>>>(rowBucket, rowCur, dis, slack, N);

    if (useFp16) {
        gather_kernel<true><<<nbuck, 512, 0, stream>>>(
            emb16, emb, dis, colBucket, colCur, out, slack, N);
    } else {
        gather_kernel<false><<<nbuck, 512, 0, stream>>>(
            nullptr, emb, dis, colBucket, colCur, out, slack, N);
    }
}

// Round 7
// 208.706 us; speedup vs baseline: 1.1601x; 1.1601x over previous
//
#include <hip/hip_runtime.h>
#include <hip/hip_fp16.h>
#include <math.h>

#define EMB_DIM 128
#define FINE_BITS 6
#define FINE_W 64           // nodes per dest bucket (= one K3 block)
#define MAXB 2048           // max coarse buckets (N <= 131072)
#define CHUNK 4096          // edges per scatter block (proven tail-parallel point)
#define MAX_SLACK 4096      // LDS sortedR capacity (slack clamped to this)
#define SB 512              // scatter block threads

// ---------------------------------------------------------------------------
// K1 (fused): blocks [0,nchunks): col-side coarse scatter; [nchunks,2*nchunks):
// row-side coarse scatter; [2*nchunks, ...): f32->fp16 embedding convert.
// Cursors are RELATIVE (zeroed by memset); absolute base = bucket*slack.
// 512 threads/block + int4 edge loads: the loops are issue/latency-bound
// (VALUBusy ~2%), so fewer load insts + more waves/block is the lever.
__global__ __launch_bounds__(SB) void scatter_cvt_kernel(
    const int* __restrict__ row, const int* __restrict__ col,
    int* __restrict__ colCur, int* __restrict__ rowCur,
    unsigned int* __restrict__ colBucket, unsigned char* __restrict__ rowBucket,
    const float* __restrict__ emb, __half* __restrict__ emb16, long long n8,
    int slack, int nchunks, int e) {
    int bid = blockIdx.x;
    int tid = threadIdx.x;
    if (bid >= 2 * nchunks) {
        // ---- cvt tail: 8 floats -> 8 halves per thread ----
        long long t = (long long)(bid - 2 * nchunks) * SB + tid;
        if (t < n8) {
            const float4* src = (const float4*)(emb) + t * 2;
            float4 a = src[0];
            float4 b = src[1];
            __half h[8];
            h[0] = __float2half(a.x); h[1] = __float2half(a.y);
            h[2] = __float2half(a.z); h[3] = __float2half(a.w);
            h[4] = __float2half(b.x); h[5] = __float2half(b.y);
            h[6] = __float2half(b.z); h[7] = __float2half(b.w);
            ((uint4*)emb16)[t] = *(const uint4*)h;
        }
        return;
    }
    __shared__ int lh[MAXB], lb[MAXB];
    bool doRow = bid >= nchunks;
    int chunk = doRow ? bid - nchunks : bid;
    int base = chunk * CHUNK;
    int lim = min(base + CHUNK, e);
    int nfull4 = (lim - base) >> 2;            // # of full int4 groups

    for (int t = tid; t < MAXB; t += SB) lh[t] = 0;
    __syncthreads();
    if (!doRow) {
        // hist pass (int4 loads)
        for (int g = tid; g < nfull4; g += SB) {
            int4 c4 = *(const int4*)(col + base + 4 * g);
            atomicAdd(&lh[c4.x >> FINE_BITS], 1);
            atomicAdd(&lh[c4.y >> FINE_BITS], 1);
            atomicAdd(&lh[c4.z >> FINE_BITS], 1);
            atomicAdd(&lh[c4.w >> FINE_BITS], 1);
        }
        for (int i = base + 4 * nfull4 + tid; i < lim; i += SB)
            atomicAdd(&lh[col[i] >> FINE_BITS], 1);
        __syncthreads();
        for (int t = tid; t < MAXB; t += SB)
            lb[t] = lh[t] ? (t * slack + atomicAdd(&colCur[t], lh[t])) : 0;
        __syncthreads();
        for (int t = tid; t < MAXB; t += SB) lh[t] = 0;
        __syncthreads();
        // placement pass (int4 loads of both col and row)
        for (int g = tid; g < nfull4; g += SB) {
            int4 c4 = *(const int4*)(col + base + 4 * g);
            int4 r4 = *(const int4*)(row + base + 4 * g);
            #pragma unroll
            for (int k = 0; k < 4; ++k) {
                int c = (&c4.x)[k], r = (&r4.x)[k];
                int cb = c >> FINE_BITS;
                int p = lb[cb] + atomicAdd(&lh[cb], 1);
                if (p < (cb + 1) * slack)
                    colBucket[p] = ((unsigned)r << FINE_BITS) | (unsigned)(c & (FINE_W - 1));
            }
        }
        for (int i = base + 4 * nfull4 + tid; i < lim; i += SB) {
            int c = col[i], r = row[i];
            int cb = c >> FINE_BITS;
            int p = lb[cb] + atomicAdd(&lh[cb], 1);
            if (p < (cb + 1) * slack)
                colBucket[p] = ((unsigned)r << FINE_BITS) | (unsigned)(c & (FINE_W - 1));
        }
    } else {
        for (int g = tid; g < nfull4; g += SB) {
            int4 r4 = *(const int4*)(row + base + 4 * g);
            atomicAdd(&lh[r4.x >> FINE_BITS], 1);
            atomicAdd(&lh[r4.y >> FINE_BITS], 1);
            atomicAdd(&lh[r4.z >> FINE_BITS], 1);
            atomicAdd(&lh[r4.w >> FINE_BITS], 1);
        }
        for (int i = base + 4 * nfull4 + tid; i < lim; i += SB)
            atomicAdd(&lh[row[i] >> FINE_BITS], 1);
        __syncthreads();
        for (int t = tid; t < MAXB; t += SB)
            lb[t] = lh[t] ? (t * slack + atomicAdd(&rowCur[t], lh[t])) : 0;
        __syncthreads();
        for (int t = tid; t < MAXB; t += SB) lh[t] = 0;
        __syncthreads();
        for (int g = tid; g < nfull4; g += SB) {
            int4 r4 = *(const int4*)(row + base + 4 * g);
            #pragma unroll
            for (int k = 0; k < 4; ++k) {
                int r = (&r4.x)[k];
                int rb = r >> FINE_BITS;
                int q = lb[rb] + atomicAdd(&lh[rb], 1);
                if (q < (rb + 1) * slack)
                    rowBucket[q] = (unsigned char)(r & (FINE_W - 1));
            }
        }
        for (int i = base + 4 * nfull4 + tid; i < lim; i += SB) {
            int r = row[i];
            int rb = r >> FINE_BITS;
            int q = lb[rb] + atomicAdd(&lh[rb], 1);
            if (q < (rb + 1) * slack)
                rowBucket[q] = (unsigned char)(r & (FINE_W - 1));
        }
    }
}

// ---------------------------------------------------------------------------
// K2: row-side fine histogram -> dis = rsqrt(1+deg). One block per bucket.
__global__ __launch_bounds__(256) void deg_kernel(
    const unsigned char* __restrict__ rowBucket, const int* __restrict__ rowCurF,
    float* __restrict__ dis, int slack, int n) {
    __shared__ int fh[FINE_W];
    int b = blockIdx.x;
    unsigned t = threadIdx.x;
    int start = b * slack;
    int end = start + min(rowCurF[b], slack);
    if (t < FINE_W) fh[t] = 0;
    __syncthreads();
    for (int i = start + (int)t; i < end; i += 256)
        atomicAdd(&fh[rowBucket[i]], 1);
    __syncthreads();
    if (t < FINE_W) {
        int node = (b << FINE_BITS) + (int)t;
        if (node < n) dis[node] = rsqrtf(1.0f + (float)fh[t]);
    }
}

// ---------------------------------------------------------------------------
// K3: bucket gather, register accumulation (round-5 proven: 68.5us, VGPR 32).
// One 512-thread block per 64-node bucket:
//   phase 1: in-block counting sort of the bucket's ~1K edges by fine node;
//   phase 2: 64 groups x 8 lanes; group g accumulates node g's contiguous
//            edge range in registers, unroll-2. Self-loop in init (norm=dc^2).
template <bool FP16>
__global__ __launch_bounds__(512) void gather_kernel(
    const __half* __restrict__ emb16, const float* __restrict__ emb,
    const float* __restrict__ dis, const unsigned int* __restrict__ colBucket,
    const int* __restrict__ colCurF, float* __restrict__ out,
    int slack, int n) {
    __shared__ int binCnt[FINE_W];
    __shared__ int binStart[FINE_W];
    __shared__ int binCur[FINE_W];
    __shared__ int sortedR[MAX_SLACK];
    __shared__ float disl[FINE_W];
    int b = blockIdx.x;
    int tid = threadIdx.x;
    int nodeBase = b << FINE_BITS;
    int start = b * slack;
    int cnt = min(colCurF[b], slack);

    if (tid < FINE_W) {
        binCnt[tid] = 0;
        int node = nodeBase + tid;
        disl[tid] = (node < n) ? dis[node] : 0.0f;
    }
    __syncthreads();

    // ---- phase 1a: fine histogram (coalesced global read, int LDS atomics)
    for (int i = tid; i < cnt; i += 512)
        atomicAdd(&binCnt[colBucket[start + i] & (FINE_W - 1)], 1);
    __syncthreads();

    // ---- phase 1b: exclusive scan of 64 bins entirely inside wave 0
    if (tid < FINE_W) {
        int v = binCnt[tid];
        int incl = v;
        #pragma unroll
        for (int d = 1; d < FINE_W; d <<= 1) {
            int u = __shfl_up(incl, d, FINE_W);
            if (tid >= d) incl += u;
        }
        binStart[tid] = incl - v;
        binCur[tid] = incl - v;
    }
    __syncthreads();

    // ---- phase 1c: scatter source ids into node-contiguous LDS order
    for (int i = tid; i < cnt; i += 512) {
        unsigned v = colBucket[start + i];
        int p = atomicAdd(&binCur[v & (FINE_W - 1)], 1);
        sortedR[p] = (int)(v >> FINE_BITS);
    }
    __syncthreads();

    // ---- phase 2: register accumulation, 8 lanes per node, 16 dims/lane
    int g = tid >> 3;        // node within bucket
    int lane = tid & 7;
    int node = nodeBase + g;
    int node_s = (node < n) ? node : 0;
    float dc = disl[g];
    float s = dc * dc;
    float4 acc0, acc1, acc2, acc3;

#define ACCUM_FP16(SRC, NRM)                                                    \
    {                                                                           \
        const uint4* hrow = (const uint4*)(emb16 + (long long)(SRC) * EMB_DIM); \
        uint4 ha = hrow[lane];                                                  \
        uint4 hb = hrow[lane + 8];                                              \
        const __half2* pa = (const __half2*)&ha;                                \
        const __half2* pb = (const __half2*)&hb;                                \
        float2 f0 = __half22float2(pa[0]), f1 = __half22float2(pa[1]);          \
        float2 f2 = __half22float2(pa[2]), f3 = __half22float2(pa[3]);          \
        float2 g0 = __half22float2(pb[0]), g1 = __half22float2(pb[1]);          \
        float2 g2 = __half22float2(pb[2]), g3 = __half22float2(pb[3]);          \
        acc0.x += (NRM) * f0.x; acc0.y += (NRM) * f0.y;                         \
        acc0.z += (NRM) * f1.x; acc0.w += (NRM) * f1.y;                         \
        acc1.x += (NRM) * f2.x; acc1.y += (NRM) * f2.y;                         \
        acc1.z += (NRM) * f3.x; acc1.w += (NRM) * f3.y;                         \
        acc2.x += (NRM) * g0.x; acc2.y += (NRM) * g0.y;                         \
        acc2.z += (NRM) * g1.x; acc2.w += (NRM) * g1.y;                         \
        acc3.x += (NRM) * g2.x; acc3.y += (NRM) * g2.y;                         \
        acc3.z += (NRM) * g3.x; acc3.w += (NRM) * g3.y;                         \
    }

#define ACCUM_FP32(SRC, NRM)                                                    \
    {                                                                           \
        const float4* frow = (const float4*)(emb + (long long)(SRC) * EMB_DIM); \
        float4 v0 = frow[2 * lane];                                             \
        float4 v1 = frow[2 * lane + 1];                                         \
        float4 v2 = frow[16 + 2 * lane];                                        \
        float4 v3 = frow[16 + 2 * lane + 1];                                    \
        acc0.x += (NRM) * v0.x; acc0.y += (NRM) * v0.y;                         \
        acc0.z += (NRM) * v0.z; acc0.w += (NRM) * v0.w;                         \
        acc1.x += (NRM) * v1.x; acc1.y += (NRM) * v1.y;                         \
        acc1.z += (NRM) * v1.z; acc1.w += (NRM) * v1.w;                         \
        acc2.x += (NRM) * v2.x; acc2.y += (NRM) * v2.y;                         \
        acc2.z += (NRM) * v2.z; acc2.w += (NRM) * v2.w;                         \
        acc3.x += (NRM) * v3.x; acc3.y += (NRM) * v3.y;                         \
        acc3.z += (NRM) * v3.z; acc3.w += (NRM) * v3.w;                         \
    }

    // self-loop init: acc = dis^2 * emb[node] (s==0 for padding rows)
    acc0 = acc1 = acc2 = acc3 = float4{0, 0, 0, 0};
    if (FP16) { ACCUM_FP16(node_s, s); } else { ACCUM_FP32(node_s, s); }

    int i = binStart[g];
    int end = i + binCnt[g];
    for (; i + 2 <= end; i += 2) {
        int s0 = sortedR[i], s1 = sortedR[i + 1];
        float n0 = dc * dis[s0];
        float n1 = dc * dis[s1];
        if (FP16) { ACCUM_FP16(s0, n0); ACCUM_FP16(s1, n1); }
        else      { ACCUM_FP32(s0, n0); ACCUM_FP32(s1, n1); }
    }
    if (i < end) {
        int s0 = sortedR[i];
        float n0 = dc * dis[s0];
        if (FP16) { ACCUM_FP16(s0, n0); } else { ACCUM_FP32(s0, n0); }
    }
#undef ACCUM_FP16
#undef ACCUM_FP32

    if (node < n) {
        float4* orow = (float4*)(out + (long long)node * EMB_DIM);
        orow[2 * lane] = acc0;
        orow[2 * lane + 1] = acc1;
        orow[16 + 2 * lane] = acc2;
        orow[16 + 2 * lane + 1] = acc3;
    }
}

extern "C" void kernel_launch(void* const* d_in, const int* in_sizes, int n_in,
                              void* d_out, int out_size, void* d_ws, size_t ws_size,
                              hipStream_t stream) {
    const int E = in_sizes[0] / 2;            // edge_index is (2, E) int32
    const int N = in_sizes[1] / EMB_DIM;      // embedding is (N, 128) f32
    const int nbuck = (N + FINE_W - 1) >> FINE_BITS;   // 1563 for N=100000

    const int* edge_index = (const int*)d_in[0];
    const int* row = edge_index;              // sources
    const int* col = edge_index + E;          // destinations
    const float* emb = (const float*)d_in[1];
    float* out = (float*)d_out;

    // slack per bucket: mean + 25% + 1024 (>>10 sigma for random edges),
    // clamped to the K3 LDS sort capacity.
    const int expected = (int)(((long long)E * FINE_W + N - 1) / N);
    int slack = expected + (expected >> 2) + 1024;
    if (slack > MAX_SLACK) slack = MAX_SLACK;
    const size_t bucketEntries = (size_t)nbuck * slack;

    char* ws = (char*)d_ws;
    size_t off = 0;
    auto alloc = [&](size_t bytes) -> void* {
        off = (off + 255) & ~(size_t)255;
        void* p = ws + off;
        off += bytes;
        return p;
    };

    size_t szEmb16 = (size_t)N * EMB_DIM * 2;
    size_t needCommon = (size_t)MAXB * 8 + (size_t)N * 4 +
                        bucketEntries * 5 + 16 * 256;
    bool useFp16 = (needCommon + szEmb16) <= ws_size;

    int*            colCur    = (int*)alloc((size_t)MAXB * 4);
    int*            rowCur    = (int*)alloc((size_t)MAXB * 4);   // adjacent to colCur
    float*          dis       = (float*)alloc((size_t)N * 4);
    unsigned int*   colBucket = (unsigned int*)alloc(bucketEntries * 4);
    unsigned char*  rowBucket = (unsigned char*)alloc(bucketEntries);
    __half*         emb16     = useFp16 ? (__half*)alloc(szEmb16) : (__half*)nullptr;

    const int nchunks = (E + CHUNK - 1) / CHUNK;
    long long n8 = useFp16 ? (long long)N * EMB_DIM / 8 : 0;
    int cvtBlocks = useFp16 ? (int)((n8 + SB - 1) / SB) : 0;

    // zero both relative cursor arrays (adjacent, MAXB*4 each, 256-aligned)
    hipMemsetAsync(colCur, 0, (size_t)MAXB * 8, stream);

    scatter_cvt_kernel<<<2 * nchunks + cvtBlocks, SB, 0, stream>>>(
        row, col, colCur, rowCur, colBucket, rowBucket,
        emb, emb16, n8, slack, nchunks, E);

    deg_kernel<<<nbuck, 256, 0, stream>>>(rowBucket, rowCur, dis, slack, N);

    if (useFp16) {
        gather_kernel<true><<<nbuck, 512, 0, stream>>>(
            emb16, emb, dis, colBucket, colCur, out, slack, N);
    } else {
        gather_kernel<false><<<nbuck, 512, 0, stream>>>(
            nullptr, emb, dis, colBucket, colCur, out, slack, N);
    }
}